// Round 7
// baseline (427.633 us; speedup 1.0000x reference)
//
#include <hip/hip_runtime.h>
#include <hip/hip_bf16.h>
#include <hip/hip_fp16.h>

// Problem constants
#define BATCH 8
#define SEQ   256
#define CDIM  768
#define DICT  16384
#define TOPK  64
#define NWIN  127          // (256-4)/2 + 1
#define NTOK  (BATCH*SEQ)  // 2048
#define SCAP  192          // screened-candidate cap per window
#define BAND  0.08f        // screening band (~7 sigma of approx wsum error)

typedef short bf16x8 __attribute__((ext_vector_type(8)));
typedef float f32x4  __attribute__((ext_vector_type(4)));
typedef _Float16 f16x8 __attribute__((ext_vector_type(8)));
typedef _Float16 f16x2 __attribute__((ext_vector_type(2)));

typedef unsigned int u32_gbl __attribute__((address_space(1)));
typedef unsigned int u32_lds __attribute__((address_space(3)));

__device__ __forceinline__ void gld_lds16(const void* g, void* l) {
    // async 16B/lane global->LDS; LDS dst = wave-uniform base + lane*16
    __builtin_amdgcn_global_load_lds((const u32_gbl*)g, (u32_lds*)l, 16, 0, 0);
}

__device__ __forceinline__ unsigned short f2bf(float f) {   // RNE
    unsigned u = __float_as_uint(f);
    return (unsigned short)((u + 0x7fffu + ((u >> 16) & 1u)) >> 16);
}
__device__ __forceinline__ float bf2f(unsigned short s) {
    return __uint_as_float(((unsigned)s) << 16);
}

// ---------------------------------------------------------------------------
// P0: convert W -> bf16, and x' = (x - b_dec) -> bf16
// ---------------------------------------------------------------------------
__global__ __launch_bounds__(256) void prep(
    const float* __restrict__ W, const float* __restrict__ x,
    const float* __restrict__ bdec,
    unsigned short* __restrict__ Wb, unsigned short* __restrict__ xb)
{
    const long long NW8 = (long long)DICT * CDIM / 8;   // 1,572,864
    const long long NX8 = (long long)NTOK * CDIM / 8;   //   196,608
    long long i = (long long)blockIdx.x * 256 + threadIdx.x;
    if (i < NW8) {
        const float4 f0 = *(const float4*)(W + i * 8);
        const float4 f1 = *(const float4*)(W + i * 8 + 4);
        int4 v;
        v.x = f2bf(f0.x) | (f2bf(f0.y) << 16);
        v.y = f2bf(f0.z) | (f2bf(f0.w) << 16);
        v.z = f2bf(f1.x) | (f2bf(f1.y) << 16);
        v.w = f2bf(f1.z) | (f2bf(f1.w) << 16);
        *(int4*)(Wb + i * 8) = v;
    } else if (i < NW8 + NX8) {
        const long long i2 = i - NW8;
        const int c = (int)((i2 * 8) % CDIM);
        const float4 f0 = *(const float4*)(x + i2 * 8);
        const float4 f1 = *(const float4*)(x + i2 * 8 + 4);
        const float4 d0 = *(const float4*)(bdec + c);
        const float4 d1 = *(const float4*)(bdec + c + 4);
        int4 v;
        v.x = f2bf(f0.x - d0.x) | (f2bf(f0.y - d0.y) << 16);
        v.y = f2bf(f0.z - d0.z) | (f2bf(f0.w - d0.w) << 16);
        v.z = f2bf(f1.x - d1.x) | (f2bf(f1.y - d1.y) << 16);
        v.w = f2bf(f1.z - d1.z) | (f2bf(f1.w - d1.w) << 16);
        *(int4*)(xb + i2 * 8) = v;
    }
}

// ---------------------------------------------------------------------------
// K1: z~ = relu(x' @ Wb^T + b_enc) via bf16 MFMA. BK=64 as two [128][32]
// sub-buffers (keeps global_load_lds lane*16 contiguity + proven LDS layout)
// -> half the barrier count. Epilogue emits wsum / zedge / zh128 (no full z~).
// ---------------------------------------------------------------------------
__global__ __launch_bounds__(256) void gemm_bf16(
    const unsigned short* __restrict__ xb,   // 2048x768 bf16
    const unsigned short* __restrict__ Wb,   // 16384x768 bf16
    const float* __restrict__ benc,
    unsigned short* __restrict__ wsum,       // (8*127) x 16384 fp16
    unsigned short* __restrict__ zedge,      // 8 x 4 x 16384 fp16
    unsigned short* __restrict__ zh128)      // 2048 x 128 fp16
{
    __shared__ char smem[128 * 136 * 2] __attribute__((aligned(16)));
    unsigned short* As0 = (unsigned short*)smem;         // k 0..31   (8 KB)
    unsigned short* Bs0 = As0 + 128 * 32;                // k 0..31   (8 KB)
    unsigned short* As1 = Bs0 + 128 * 32;                // k 32..63  (8 KB)
    unsigned short* Bs1 = As1 + 128 * 32;                // k 32..63  (8 KB)
    _Float16* Cs = (_Float16*)smem;                      // 128*136 f16 (aliases)

    const int tid = threadIdx.x;
    const int lane = tid & 63, w = tid >> 6;
    const int m0 = blockIdx.x * 128, n0 = blockIdx.y * 128;

    // staging: wave w covers rows 32w..32w+31 in two 16-row issues per buffer
    const int r0 = 32 * w + (lane >> 2);
    const int kb = (lane & 3) * 8;               // k element offset (0..24)
    const unsigned short* gA0 = xb + (size_t)(m0 + r0) * CDIM + kb;
    const unsigned short* gA1 = xb + (size_t)(m0 + r0 + 16) * CDIM + kb;
    const unsigned short* gB0 = Wb + (size_t)(n0 + r0) * CDIM + kb;
    const unsigned short* gB1 = Wb + (size_t)(n0 + r0 + 16) * CDIM + kb;
    unsigned short* lA0 = As0 + (2 * w + 0) * 512;
    unsigned short* lA1 = As0 + (2 * w + 1) * 512;
    unsigned short* lB0 = Bs0 + (2 * w + 0) * 512;
    unsigned short* lB1 = Bs0 + (2 * w + 1) * 512;
    unsigned short* lA0b = As1 + (2 * w + 0) * 512;
    unsigned short* lA1b = As1 + (2 * w + 1) * 512;
    unsigned short* lB0b = Bs1 + (2 * w + 0) * 512;
    unsigned short* lB1b = Bs1 + (2 * w + 1) * 512;

    const int wm = (w & 1) * 64, wn = (w >> 1) * 64;
    const int m16 = lane & 15, qd = lane >> 4;

    f32x4 acc[4][4] = {};

    for (int kc = 0; kc < CDIM; kc += 64) {
        __syncthreads();                         // prior reads done
        gld_lds16(gA0 + kc, lA0);
        gld_lds16(gA1 + kc, lA1);
        gld_lds16(gB0 + kc, lB0);
        gld_lds16(gB1 + kc, lB1);
        gld_lds16(gA0 + kc + 32, lA0b);
        gld_lds16(gA1 + kc + 32, lA1b);
        gld_lds16(gB0 + kc + 32, lB0b);
        gld_lds16(gB1 + kc + 32, lB1b);
        __syncthreads();                         // staging visible (vmcnt drain)

        {
            bf16x8 af[4], bf[4];
#pragma unroll
            for (int i = 0; i < 4; i++)
                af[i] = *(const bf16x8*)(&As0[(wm + 16 * i + m16) * 32 + qd * 8]);
#pragma unroll
            for (int j = 0; j < 4; j++)
                bf[j] = *(const bf16x8*)(&Bs0[(wn + 16 * j + m16) * 32 + qd * 8]);
#pragma unroll
            for (int i = 0; i < 4; i++)
#pragma unroll
                for (int j = 0; j < 4; j++)
                    acc[i][j] = __builtin_amdgcn_mfma_f32_16x16x32_bf16(
                        af[i], bf[j], acc[i][j], 0, 0, 0);
        }
        {
            bf16x8 af[4], bf[4];
#pragma unroll
            for (int i = 0; i < 4; i++)
                af[i] = *(const bf16x8*)(&As1[(wm + 16 * i + m16) * 32 + qd * 8]);
#pragma unroll
            for (int j = 0; j < 4; j++)
                bf[j] = *(const bf16x8*)(&Bs1[(wn + 16 * j + m16) * 32 + qd * 8]);
#pragma unroll
            for (int i = 0; i < 4; i++)
#pragma unroll
                for (int j = 0; j < 4; j++)
                    acc[i][j] = __builtin_amdgcn_mfma_f32_16x16x32_bf16(
                        af[i], bf[j], acc[i][j], 0, 0, 0);
        }
    }
    __syncthreads();                             // all waves done with As/Bs (Cs aliases)

    // epilogue: +b_enc, relu -> Cs (fp16).  C/D layout: col=lane&15, row=qd*4+r
#pragma unroll
    for (int j = 0; j < 4; j++) {
        const int col = wn + 16 * j + m16;
        const float bc = benc[n0 + col];
#pragma unroll
        for (int i = 0; i < 4; i++) {
            const int row = wm + 16 * i + qd * 4;
            const f32x4 a = acc[i][j];
#pragma unroll
            for (int r = 0; r < 4; r++)
                Cs[(row + r) * 136 + col] = (_Float16)fmaxf(a[r] + bc, 0.0f);
        }
    }
    __syncthreads();

    const int b = m0 >> 8;                       // batch
    const int tloc = m0 & 255;                   // 0 or 128 within batch
    const int wbase = (tloc == 0) ? 0 : 64;

    // 63 interior windows: wsum[w][col] = sum of 4 consecutive Cs rows (f16x2)
    for (int u = tid; u < 63 * 64; u += 256) {
        const int i = u >> 6, cp = (u & 63) * 2;
        const _Float16* cb = &Cs[(2 * i) * 136 + cp];
        const f16x2 p0 = *(const f16x2*)(cb);
        const f16x2 p1 = *(const f16x2*)(cb + 136);
        const f16x2 p2 = *(const f16x2*)(cb + 272);
        const f16x2 p3 = *(const f16x2*)(cb + 408);
        f16x2 v;
        v[0] = (_Float16)(((float)p0[0] + (float)p1[0]) + ((float)p2[0] + (float)p3[0]));
        v[1] = (_Float16)(((float)p0[1] + (float)p1[1]) + ((float)p2[1] + (float)p3[1]));
        *(f16x2*)((_Float16*)wsum + (size_t)(b * NWIN + wbase + i) * DICT + n0 + cp) = v;
    }

    // crossing-window rows: tloc==0 -> local rows 126,127 (slots 0,1);
    //                       tloc==128 -> local rows 0,1 (slots 2,3)
    if (tid < 128) {
        const int rr = tid >> 6, cp = (tid & 63) * 2;
        const int lr0 = (tloc == 0) ? 126 : 0;
        const int slot0 = (tloc == 0) ? 0 : 2;
        const f16x2 v = *(const f16x2*)(&Cs[(lr0 + rr) * 136 + cp]);
        *(f16x2*)((_Float16*)zedge + (size_t)(b * 4 + slot0 + rr) * DICT + n0 + cp) = v;
    }

    // z~ cols 0..127 for the zero-fill rule (n-block 0 only)
    if (n0 == 0) {
        for (int u = tid; u < 2048; u += 256) {  // 128 rows x 16 segs of 16B
            const int m = u >> 4, seg = u & 15;
            const int4 v = *(const int4*)(&Cs[m * 136 + seg * 8]);
            *(int4*)((_Float16*)zh128 + (size_t)(m0 + m) * 128 + seg * 8) = v;
        }
    }
}

// ---------------------------------------------------------------------------
// K2: per-window screen from precomputed wsum (w==63 from zedge rows),
// 64th-largest via bit search, emit S = { d : wsum~ > tau~ - BAND }
// ---------------------------------------------------------------------------
__global__ __launch_bounds__(256) void win_screen(
    const unsigned short* __restrict__ wsum, const unsigned short* __restrict__ zedge,
    int* __restrict__ Scnt, int* __restrict__ Sidx)
{
    const int wid = blockIdx.x;
    const int b = wid / NWIN, w = wid % NWIN;
    const int tid = threadIdx.x;

    float wv[64];
    if (w != 63) {
        const _Float16* row = (const _Float16*)wsum + (size_t)wid * DICT;
#pragma unroll
        for (int c = 0; c < 8; c++) {
            const f16x8 r0 = *(const f16x8*)(row + (c * 256 + tid) * 8);
#pragma unroll
            for (int e = 0; e < 8; e++) wv[c * 8 + e] = (float)r0[e];
        }
    } else {
        const _Float16* e0 = (const _Float16*)zedge + (size_t)b * 4 * DICT;
#pragma unroll
        for (int c = 0; c < 8; c++) {
            const int d8 = (c * 256 + tid) * 8;
            const f16x8 r0 = *(const f16x8*)(e0 + d8);
            const f16x8 r1 = *(const f16x8*)(e0 + DICT + d8);
            const f16x8 r2 = *(const f16x8*)(e0 + 2 * DICT + d8);
            const f16x8 r3 = *(const f16x8*)(e0 + 3 * DICT + d8);
#pragma unroll
            for (int e = 0; e < 8; e++)
                wv[c * 8 + e] = (((float)r0[e] + (float)r1[e]) + (float)r2[e]) + (float)r3[e];
        }
    }

    __shared__ int red[4];
    __shared__ int s_cnt;

    unsigned lo = 0u, hi = 0x43000000u;        // 128.0f
    while (lo < hi) {
        const unsigned mid = (lo + hi) >> 1;
        const float fm = __uint_as_float(mid);
        int c = 0;
#pragma unroll
        for (int j = 0; j < 64; j++) c += (wv[j] > fm) ? 1 : 0;
        for (int off = 32; off > 0; off >>= 1) c += __shfl_down(c, off);
        if ((tid & 63) == 0) red[tid >> 6] = c;
        __syncthreads();
        const int tot = red[0] + red[1] + red[2] + red[3];
        __syncthreads();
        if (tot >= 64) lo = mid + 1; else hi = mid;
    }
    const float thr = __uint_as_float(lo) - BAND;

    if (tid == 0) s_cnt = 0;
    __syncthreads();
#pragma unroll
    for (int c = 0; c < 8; c++) {
#pragma unroll
        for (int e = 0; e < 8; e++) {
            if (wv[c * 8 + e] > thr) {
                const int s = atomicAdd(&s_cnt, 1);
                if (s < SCAP) Sidx[wid * SCAP + s] = (c * 256 + tid) * 8 + e;
            }
        }
    }
    __syncthreads();
    if (tid == 0) Scnt[wid] = (s_cnt < SCAP) ? s_cnt : SCAP;
}

// ---------------------------------------------------------------------------
// K3: per-window exact fp32 recompute for screened set, exact top-64.
// xd register-resident; per candidate 3 coalesced float4 W loads (+prefetch).
// ---------------------------------------------------------------------------
__global__ __launch_bounds__(256) void win_exact(
    const float* __restrict__ x, const float* __restrict__ W,
    const float* __restrict__ benc, const float* __restrict__ bdec,
    const int* __restrict__ Scnt, const int* __restrict__ Sidx,
    int* __restrict__ win_idx, float* __restrict__ ztab)
{
    const int wid = blockIdx.x;
    const int b = wid / NWIN, w = wid % NWIN;
    const int t0 = 2 * w;
    const int tid = threadIdx.x;
    const int lane = tid & 63, wvi = tid >> 6;

    __shared__ float swsum[SCAP];
    __shared__ float sz[SCAP][4];
    __shared__ int sd[SCAP];
    __shared__ int red[4];
    __shared__ int s_n1, s_eqc;
    __shared__ int eq_d[SCAP], eq_s[SCAP];
    __shared__ int out_slot[64];

    const int cnt = min(Scnt[wid], SCAP);
    const float* xrow = x + (size_t)(b * SEQ + t0) * CDIM;

    // xd[r][e] = (x[t0+r] - bdec) at columns lane*4 + e*256 .. +3
    float4 xd[4][3];
#pragma unroll
    for (int e = 0; e < 3; e++) {
        const int c = lane * 4 + e * 256;
        const float4 bd = *(const float4*)(bdec + c);
#pragma unroll
        for (int r = 0; r < 4; r++) {
            const float4 xv = *(const float4*)(xrow + r * CDIM + c);
            xd[r][e].x = xv.x - bd.x; xd[r][e].y = xv.y - bd.y;
            xd[r][e].z = xv.z - bd.z; xd[r][e].w = xv.w - bd.w;
        }
    }

    // candidate loop: one candidate per wave, 1-deep W prefetch
    int s = wvi;
    int dcur = -1;
    float4 wv0, wv1, wv2;
    if (s < cnt) {
        dcur = Sidx[wid * SCAP + s];
        const float* wr = W + (size_t)dcur * CDIM + lane * 4;
        wv0 = *(const float4*)(wr);
        wv1 = *(const float4*)(wr + 256);
        wv2 = *(const float4*)(wr + 512);
    }
    while (s < cnt) {
        const int snx = s + 4;
        int dnx = -1;
        float4 wn0, wn1, wn2;
        if (snx < cnt) {
            dnx = Sidx[wid * SCAP + snx];
            const float* wr = W + (size_t)dnx * CDIM + lane * 4;
            wn0 = *(const float4*)(wr);
            wn1 = *(const float4*)(wr + 256);
            wn2 = *(const float4*)(wr + 512);
        }
        float a0 = 0.f, a1 = 0.f, a2 = 0.f, a3 = 0.f;
        {
            const float4 wvv[3] = {wv0, wv1, wv2};
#pragma unroll
            for (int e = 0; e < 3; e++) {
                a0 = fmaf(xd[0][e].x, wvv[e].x, a0);
                a0 = fmaf(xd[0][e].y, wvv[e].y, a0);
                a0 = fmaf(xd[0][e].z, wvv[e].z, a0);
                a0 = fmaf(xd[0][e].w, wvv[e].w, a0);
                a1 = fmaf(xd[1][e].x, wvv[e].x, a1);
                a1 = fmaf(xd[1][e].y, wvv[e].y, a1);
                a1 = fmaf(xd[1][e].z, wvv[e].z, a1);
                a1 = fmaf(xd[1][e].w, wvv[e].w, a1);
                a2 = fmaf(xd[2][e].x, wvv[e].x, a2);
                a2 = fmaf(xd[2][e].y, wvv[e].y, a2);
                a2 = fmaf(xd[2][e].z, wvv[e].z, a2);
                a2 = fmaf(xd[2][e].w, wvv[e].w, a2);
                a3 = fmaf(xd[3][e].x, wvv[e].x, a3);
                a3 = fmaf(xd[3][e].y, wvv[e].y, a3);
                a3 = fmaf(xd[3][e].z, wvv[e].z, a3);
                a3 = fmaf(xd[3][e].w, wvv[e].w, a3);
            }
        }
#pragma unroll
        for (int off = 32; off > 0; off >>= 1) {
            a0 += __shfl_xor(a0, off); a1 += __shfl_xor(a1, off);
            a2 += __shfl_xor(a2, off); a3 += __shfl_xor(a3, off);
        }
        if (lane == 0) {
            const float be = benc[dcur];
            const float z0 = fmaxf(a0 + be, 0.f), z1 = fmaxf(a1 + be, 0.f);
            const float z2 = fmaxf(a2 + be, 0.f), z3 = fmaxf(a3 + be, 0.f);
            sd[s] = dcur;
            sz[s][0] = z0; sz[s][1] = z1; sz[s][2] = z2; sz[s][3] = z3;
            swsum[s] = ((z0 + z1) + z2) + z3;
        }
        s = snx; dcur = dnx;
        wv0 = wn0; wv1 = wn1; wv2 = wn2;
    }
    __syncthreads();

    const float v = (tid < cnt) ? swsum[tid] : -1.0f;
    unsigned lo = 0u, hi = 0x43000000u;
    while (lo < hi) {
        const unsigned mid = (lo + hi) >> 1;
        const float fm = __uint_as_float(mid);
        int c = (v > fm) ? 1 : 0;
        for (int off = 32; off > 0; off >>= 1) c += __shfl_down(c, off);
        if ((tid & 63) == 0) red[tid >> 6] = c;
        __syncthreads();
        const int tot = red[0] + red[1] + red[2] + red[3];
        __syncthreads();
        if (tot >= 64) lo = mid + 1; else hi = mid;
    }
    const float tau = __uint_as_float(lo);

    if (tid == 0) { s_n1 = 0; s_eqc = 0; }
    __syncthreads();
    if (tid < cnt) {
        if (v > tau) { const int sl = atomicAdd(&s_n1, 1); out_slot[sl] = tid; }
        else if (v == tau) {
            const int sl = atomicAdd(&s_eqc, 1);
            if (sl < SCAP) { eq_d[sl] = sd[tid]; eq_s[sl] = tid; }
        }
    }
    __syncthreads();
    if (tid == 0) {
        const int n1 = s_n1, need = 64 - n1;
        int ec = min(s_eqc, SCAP);
        for (int a = 0; a < need; a++) {          // lowest-index-first fill
            int best = a;
            for (int q = a + 1; q < ec; q++)
                if (eq_d[q] < eq_d[best]) best = q;
            int td = eq_d[a]; eq_d[a] = eq_d[best]; eq_d[best] = td;
            int ts = eq_s[a]; eq_s[a] = eq_s[best]; eq_s[best] = ts;
            out_slot[n1 + a] = eq_s[a];
        }
    }
    __syncthreads();
    if (tid < 64) {
        const int sl = out_slot[tid];
        win_idx[wid * 64 + tid] = sd[sl];
        float* zt = ztab + (size_t)(wid * 64 + tid) * 4;
        zt[0] = sz[sl][0]; zt[1] = sz[sl][1]; zt[2] = sz[sl][2]; zt[3] = sz[sl][3];
    }
}

// ---------------------------------------------------------------------------
// K5: per-token final top-64 of fv. Selected values exact (ztab); zero-fill
// values approx from fp16 zh128 (fill indices provably < 128; tol 0.109).
// ---------------------------------------------------------------------------
__global__ __launch_bounds__(64) void tok_topk(
    const int* __restrict__ win_idx, const float* __restrict__ ztab,
    const unsigned short* __restrict__ zh128,
    int* __restrict__ tok_idx, float* __restrict__ tok_val)
{
    const int bid = blockIdx.x;            // token = b*256 + t
    const int t = bid & 255, b = bid >> 8;
    const int lane = threadIdx.x;
    const int wlo = (t >= 2) ? ((t - 2) >> 1) : 0;
    int whi = t >> 1; if (whi > NWIN - 1) whi = NWIN - 1;

    __shared__ int l1[64], l2[64];
    __shared__ int out_i[64];
    __shared__ float out_v[64];
    __shared__ int eq_i[130];
    __shared__ float eq_v[130];
    __shared__ int cnt, eqc;

    const int g1 = (b * NWIN + wlo) * 64 + lane;
    const int idx1 = win_idx[g1];
    const float z1 = ztab[(size_t)g1 * 4 + (t - 2 * wlo)];
    const bool valid2 = (whi != wlo);
    int idx2 = -1; float z2 = 0.f;
    if (valid2) {
        const int g2 = (b * NWIN + whi) * 64 + lane;
        idx2 = win_idx[g2];
        z2 = ztab[(size_t)g2 * 4 + (t - 2 * whi)];
    }
    l1[lane] = idx1; l2[lane] = idx2;
    if (lane == 0) { cnt = 0; eqc = 0; }
    __syncthreads();

    bool in2 = false, dup2 = false;
    for (int j = 0; j < 64; j++) {
        in2  |= (idx1 == l2[j]);
        dup2 |= (idx2 == l1[j]);
    }
    const float fv1 = in2 ? 2.0f * z1 : z1;
    const bool c2 = valid2 && !dup2;
    const float fv2 = c2 ? z2 : 0.0f;
    const bool pos1 = (fv1 > 0.0f);
    const bool pos2 = c2 && (fv2 > 0.0f);
    const unsigned long long m1 = __ballot(pos1);
    const unsigned long long m2 = __ballot(pos2);
    const int npos = __popcll(m1) + __popcll(m2);

    if (npos > 64) {
        unsigned lo = 0u, hi = 0x43000000u;
        while (lo < hi) {
            const unsigned mid = (lo + hi) >> 1;
            const float fm = __uint_as_float(mid);
            const int c = __popcll(__ballot(pos1 && fv1 > fm)) +
                          __popcll(__ballot(pos2 && fv2 > fm));
            if (c >= 64) lo = mid + 1; else hi = mid;
        }
        const float tau = __uint_as_float(lo);
        const int n1 = __popcll(__ballot(pos1 && fv1 > tau)) +
                       __popcll(__ballot(pos2 && fv2 > tau));
        if (pos1 && fv1 > tau) { const int s = atomicAdd(&cnt, 1); out_i[s] = idx1; out_v[s] = z1; }
        if (pos2 && fv2 > tau) { const int s = atomicAdd(&cnt, 1); out_i[s] = idx2; out_v[s] = z2; }
        if (pos1 && fv1 == tau) { const int s = atomicAdd(&eqc, 1); if (s < 130) { eq_i[s] = idx1; eq_v[s] = z1; } }
        if (pos2 && fv2 == tau) { const int s = atomicAdd(&eqc, 1); if (s < 130) { eq_i[s] = idx2; eq_v[s] = z2; } }
        __syncthreads();
        if (lane == 0) {
            const int need = 64 - n1;
            int ec = (eqc < 130) ? eqc : 130;
            for (int a = 0; a < need; a++) {
                int best = a;
                for (int q = a + 1; q < ec; q++)
                    if (eq_i[q] < eq_i[best]) best = q;
                const int ti = eq_i[a]; eq_i[a] = eq_i[best]; eq_i[best] = ti;
                const float tv = eq_v[a]; eq_v[a] = eq_v[best]; eq_v[best] = tv;
                out_i[n1 + a] = eq_i[a]; out_v[n1 + a] = eq_v[a];
            }
        }
    } else {
        if (pos1) { const int s = atomicAdd(&cnt, 1); out_i[s] = idx1; out_v[s] = z1; }
        if (pos2) { const int s = atomicAdd(&cnt, 1); out_i[s] = idx2; out_v[s] = z2; }
        const int need = 64 - npos;
        const int d1 = lane, d2 = lane + 64;
        bool ip1 = false, ip2 = false;
        for (int j = 0; j < 64; j++) {
            const int o1 = l1[j]; const bool p1 = (m1 >> j) & 1ull;
            const int o2 = l2[j]; const bool p2 = (m2 >> j) & 1ull;
            ip1 |= (p1 && o1 == d1) || (p2 && o2 == d1);
            ip2 |= (p1 && o1 == d2) || (p2 && o2 == d2);
        }
        const unsigned long long av1 = __ballot(!ip1);
        const unsigned long long av2 = __ballot(!ip2);
        const unsigned long long below = (1ull << lane) - 1ull;
        const int r1 = __popcll(av1 & below);
        const int na1 = __popcll(av1);
        const int r2 = na1 + __popcll(av2 & below);
        if (!ip1 && r1 < need) {
            bool incand = false;
            for (int j = 0; j < 64; j++) incand |= (l1[j] == d1) || (l2[j] == d1);
            // in-candidate fv==0 implies exact z==0; else use fp16 approx value
            const float zv = incand ? 0.0f
                : (float)((const _Float16*)zh128)[(size_t)bid * 128 + d1];
            const int s = atomicAdd(&cnt, 1); out_i[s] = d1; out_v[s] = zv;
        }
        if (!ip2 && r2 < need) {
            bool incand = false;
            for (int j = 0; j < 64; j++) incand |= (l1[j] == d2) || (l2[j] == d2);
            const float zv = incand ? 0.0f
                : (float)((const _Float16*)zh128)[(size_t)bid * 128 + d2];
            const int s = atomicAdd(&cnt, 1); out_i[s] = d2; out_v[s] = zv;
        }
    }
    __syncthreads();
    tok_idx[bid * 64 + lane] = out_i[lane];
    tok_val[bid * 64 + lane] = out_v[lane];
}

// ---------------------------------------------------------------------------
// K6: recon from bf16 W rows. v2: 192 threads/block, lane owns 4 CONSECUTIVE
// cols -> one 8B uint2 load per W row (fully coalesced), 64 loads/thread.
// Replaces 192 scalar 2B loads/thread (latency-bound like old zfill).
// ---------------------------------------------------------------------------
__global__ __launch_bounds__(192) void recon_k(
    const int* __restrict__ tok_idx, const float* __restrict__ tok_val,
    const unsigned short* __restrict__ Wb, const float* __restrict__ bdec,
    float* __restrict__ recon)
{
    const int bid = blockIdx.x;
    const int tid = threadIdx.x;          // 0..191
    __shared__ int si[64];
    __shared__ float sv[64];
    if (tid < 64) { si[tid] = tok_idx[bid * 64 + tid]; sv[tid] = tok_val[bid * 64 + tid]; }
    __syncthreads();

    const int c = tid * 4;                // 4 consecutive cols, 8B aligned in Wb
    const float4 bd = *(const float4*)(bdec + c);
    float a0 = bd.x, a1 = bd.y, a2 = bd.z, a3 = bd.w;
#pragma unroll 8
    for (int j = 0; j < 64; j++) {
        const uint2 pv = *(const uint2*)(Wb + (size_t)si[j] * CDIM + c);
        const float vj = sv[j];
        a0 = fmaf(vj, bf2f((unsigned short)(pv.x & 0xffffu)), a0);
        a1 = fmaf(vj, bf2f((unsigned short)(pv.x >> 16)), a1);
        a2 = fmaf(vj, bf2f((unsigned short)(pv.y & 0xffffu)), a2);
        a3 = fmaf(vj, bf2f((unsigned short)(pv.y >> 16)), a3);
    }
    float4 o; o.x = a0; o.y = a1; o.z = a2; o.w = a3;
    *(float4*)(recon + (size_t)bid * CDIM + c) = o;
}

// ---------------------------------------------------------------------------
// K7: fused zero + scatter (replaces memset + scatter; no write amplification)
// ---------------------------------------------------------------------------
__global__ __launch_bounds__(256) void zero_scatter(
    const int* __restrict__ tok_idx, const float* __restrict__ tok_val,
    float* __restrict__ enc)
{
    const int bid = blockIdx.x;
    const int tid = threadIdx.x;
    float* row = enc + (size_t)bid * DICT;
    const float4 z4 = {0.f, 0.f, 0.f, 0.f};
#pragma unroll
    for (int k = 0; k < 16; k++)                 // 256 thr * 16 * 4 = 16384
        *(float4*)(row + (k * 256 + tid) * 4) = z4;
    __syncthreads();
    if (tid < 64)
        row[tok_idx[bid * 64 + tid]] = tok_val[bid * 64 + tid];
}

// ---------------------------------------------------------------------------
extern "C" void kernel_launch(void* const* d_in, const int* in_sizes, int n_in,
                              void* d_out, int out_size, void* d_ws, size_t ws_size,
                              hipStream_t stream)
{
    const float* x    = (const float*)d_in[0];
    const float* Wenc = (const float*)d_in[1];
    const float* benc = (const float*)d_in[2];
    const float* bdec = (const float*)d_in[4];
    (void)in_sizes; (void)n_in; (void)out_size; (void)ws_size;

    float* recon = (float*)d_out;
    float* enc   = recon + (size_t)NTOK * CDIM;          // 134,217,728 bytes

    // scratch layout inside the enc output region (all consumed pre-zero)
    char* base = (char*)enc;
    unsigned short* wsum  = (unsigned short*)(base);                 // 33,292,288
    unsigned short* Wb    = (unsigned short*)(base + 33292288);      // 25,165,824
    unsigned short* xb    = (unsigned short*)(base + 58458112);      //  3,145,728
    unsigned short* zedge = (unsigned short*)(base + 61603840);      //  1,048,576
    unsigned short* zh128 = (unsigned short*)(base + 62652416);      //    524,288
    int*   Scnt           = (int*)(base + 63176704);                 //      4,096
    int*   Sidx           = (int*)(base + 63180800);                 //    780,288
    int*   wini           = (int*)(base + 63961088);                 //    260,096
    float* ztab           = (float*)(base + 64221184);               //  1,040,384

    // tok lists must survive the zeroing -> d_ws (1.0 MB)
    int*   tok_i = (int*)d_ws;
    float* tok_v = (float*)((char*)d_ws + (size_t)NTOK * 64 * 4);

    prep<<<dim3(6912), 256, 0, stream>>>(Wenc, x, bdec, Wb, xb);
    gemm_bf16<<<dim3(NTOK / 128, DICT / 128), 256, 0, stream>>>(xb, Wb, benc,
                                                                wsum, zedge, zh128);
    win_screen<<<dim3(BATCH * NWIN), 256, 0, stream>>>(wsum, zedge, Scnt, Sidx);
    win_exact<<<dim3(BATCH * NWIN), 256, 0, stream>>>(x, Wenc, benc, bdec,
                                                      Scnt, Sidx, wini, ztab);
    tok_topk<<<dim3(NTOK), 64, 0, stream>>>(wini, ztab, zh128, tok_i, tok_v);
    recon_k<<<dim3(NTOK), 192, 0, stream>>>(tok_i, tok_v, Wb, bdec, recon);
    zero_scatter<<<dim3(NTOK), 256, 0, stream>>>(tok_i, tok_v, enc);
}

// Round 8
// 412.013 us; speedup vs baseline: 1.0379x; 1.0379x over previous
//
#include <hip/hip_runtime.h>
#include <hip/hip_bf16.h>
#include <hip/hip_fp16.h>

// Problem constants
#define BATCH 8
#define SEQ   256
#define CDIM  768
#define DICT  16384
#define TOPK  64
#define NWIN  127          // (256-4)/2 + 1
#define NTOK  (BATCH*SEQ)  // 2048
#define SCAP  192          // screened-candidate cap per window
#define BAND  0.08f        // screening band (~7 sigma of approx wsum error)

typedef short bf16x8 __attribute__((ext_vector_type(8)));
typedef float f32x4  __attribute__((ext_vector_type(4)));
typedef _Float16 f16x8 __attribute__((ext_vector_type(8)));
typedef _Float16 f16x4 __attribute__((ext_vector_type(4)));
typedef _Float16 f16x2 __attribute__((ext_vector_type(2)));

typedef unsigned int u32_gbl __attribute__((address_space(1)));
typedef unsigned int u32_lds __attribute__((address_space(3)));

__device__ __forceinline__ void gld_lds16(const void* g, void* l) {
    // async 16B/lane global->LDS; LDS dst = wave-uniform base + lane*16
    __builtin_amdgcn_global_load_lds((const u32_gbl*)g, (u32_lds*)l, 16, 0, 0);
}

__device__ __forceinline__ unsigned short f2bf(float f) {   // RNE
    unsigned u = __float_as_uint(f);
    return (unsigned short)((u + 0x7fffu + ((u >> 16) & 1u)) >> 16);
}
__device__ __forceinline__ float bf2f(unsigned short s) {
    return __uint_as_float(((unsigned)s) << 16);
}

// ---------------------------------------------------------------------------
// P0: convert W -> bf16, and x' = (x - b_dec) -> bf16
// ---------------------------------------------------------------------------
__global__ __launch_bounds__(256) void prep(
    const float* __restrict__ W, const float* __restrict__ x,
    const float* __restrict__ bdec,
    unsigned short* __restrict__ Wb, unsigned short* __restrict__ xb)
{
    const long long NW8 = (long long)DICT * CDIM / 8;   // 1,572,864
    const long long NX8 = (long long)NTOK * CDIM / 8;   //   196,608
    long long i = (long long)blockIdx.x * 256 + threadIdx.x;
    if (i < NW8) {
        const float4 f0 = *(const float4*)(W + i * 8);
        const float4 f1 = *(const float4*)(W + i * 8 + 4);
        int4 v;
        v.x = f2bf(f0.x) | (f2bf(f0.y) << 16);
        v.y = f2bf(f0.z) | (f2bf(f0.w) << 16);
        v.z = f2bf(f1.x) | (f2bf(f1.y) << 16);
        v.w = f2bf(f1.z) | (f2bf(f1.w) << 16);
        *(int4*)(Wb + i * 8) = v;
    } else if (i < NW8 + NX8) {
        const long long i2 = i - NW8;
        const int c = (int)((i2 * 8) % CDIM);
        const float4 f0 = *(const float4*)(x + i2 * 8);
        const float4 f1 = *(const float4*)(x + i2 * 8 + 4);
        const float4 d0 = *(const float4*)(bdec + c);
        const float4 d1 = *(const float4*)(bdec + c + 4);
        int4 v;
        v.x = f2bf(f0.x - d0.x) | (f2bf(f0.y - d0.y) << 16);
        v.y = f2bf(f0.z - d0.z) | (f2bf(f0.w - d0.w) << 16);
        v.z = f2bf(f1.x - d1.x) | (f2bf(f1.y - d1.y) << 16);
        v.w = f2bf(f1.z - d1.z) | (f2bf(f1.w - d1.w) << 16);
        *(int4*)(xb + i2 * 8) = v;
    }
}

// ---------------------------------------------------------------------------
// K1: z~ = relu(x' @ Wb^T + b_enc) via bf16 MFMA. BK=64 (two [128][32] LDS
// sub-buffers). Epilogue v2: C stored TRANSPOSED CsT[col][row] (pad 136) ->
// lane writes f16x4 (b64) per acc quad; wsum computed per-column with
// ds_read_b128s; emits wsum / zedge / zh128 (full z~ never materialized).
// ---------------------------------------------------------------------------
__global__ __launch_bounds__(256) void gemm_bf16(
    const unsigned short* __restrict__ xb,   // 2048x768 bf16
    const unsigned short* __restrict__ Wb,   // 16384x768 bf16
    const float* __restrict__ benc,
    unsigned short* __restrict__ wsum,       // (8*127) x 16384 fp16
    unsigned short* __restrict__ zedge,      // 8 x 4 x 16384 fp16
    unsigned short* __restrict__ zh128)      // 2048 x 128 fp16
{
    __shared__ char smem[128 * 136 * 2] __attribute__((aligned(16)));
    unsigned short* As0 = (unsigned short*)smem;         // k 0..31   (8 KB)
    unsigned short* Bs0 = As0 + 128 * 32;                // k 0..31   (8 KB)
    unsigned short* As1 = Bs0 + 128 * 32;                // k 32..63  (8 KB)
    unsigned short* Bs1 = As1 + 128 * 32;                // k 32..63  (8 KB)
    _Float16* CsT = (_Float16*)smem;                     // [128 cols][136 rows] (aliases)

    const int tid = threadIdx.x;
    const int lane = tid & 63, w = tid >> 6;
    const int m0 = blockIdx.x * 128, n0 = blockIdx.y * 128;

    // staging: wave w covers rows 32w..32w+31 in two 16-row issues per buffer
    const int r0 = 32 * w + (lane >> 2);
    const int kb = (lane & 3) * 8;               // k element offset (0..24)
    const unsigned short* gA0 = xb + (size_t)(m0 + r0) * CDIM + kb;
    const unsigned short* gA1 = xb + (size_t)(m0 + r0 + 16) * CDIM + kb;
    const unsigned short* gB0 = Wb + (size_t)(n0 + r0) * CDIM + kb;
    const unsigned short* gB1 = Wb + (size_t)(n0 + r0 + 16) * CDIM + kb;
    unsigned short* lA0 = As0 + (2 * w + 0) * 512;
    unsigned short* lA1 = As0 + (2 * w + 1) * 512;
    unsigned short* lB0 = Bs0 + (2 * w + 0) * 512;
    unsigned short* lB1 = Bs0 + (2 * w + 1) * 512;
    unsigned short* lA0b = As1 + (2 * w + 0) * 512;
    unsigned short* lA1b = As1 + (2 * w + 1) * 512;
    unsigned short* lB0b = Bs1 + (2 * w + 0) * 512;
    unsigned short* lB1b = Bs1 + (2 * w + 1) * 512;

    const int wm = (w & 1) * 64, wn = (w >> 1) * 64;
    const int m16 = lane & 15, qd = lane >> 4;

    f32x4 acc[4][4] = {};

    for (int kc = 0; kc < CDIM; kc += 64) {
        __syncthreads();                         // prior reads done
        gld_lds16(gA0 + kc, lA0);
        gld_lds16(gA1 + kc, lA1);
        gld_lds16(gB0 + kc, lB0);
        gld_lds16(gB1 + kc, lB1);
        gld_lds16(gA0 + kc + 32, lA0b);
        gld_lds16(gA1 + kc + 32, lA1b);
        gld_lds16(gB0 + kc + 32, lB0b);
        gld_lds16(gB1 + kc + 32, lB1b);
        __syncthreads();                         // staging visible (vmcnt drain)

        {
            bf16x8 af[4], bf[4];
#pragma unroll
            for (int i = 0; i < 4; i++)
                af[i] = *(const bf16x8*)(&As0[(wm + 16 * i + m16) * 32 + qd * 8]);
#pragma unroll
            for (int j = 0; j < 4; j++)
                bf[j] = *(const bf16x8*)(&Bs0[(wn + 16 * j + m16) * 32 + qd * 8]);
#pragma unroll
            for (int i = 0; i < 4; i++)
#pragma unroll
                for (int j = 0; j < 4; j++)
                    acc[i][j] = __builtin_amdgcn_mfma_f32_16x16x32_bf16(
                        af[i], bf[j], acc[i][j], 0, 0, 0);
        }
        {
            bf16x8 af[4], bf[4];
#pragma unroll
            for (int i = 0; i < 4; i++)
                af[i] = *(const bf16x8*)(&As1[(wm + 16 * i + m16) * 32 + qd * 8]);
#pragma unroll
            for (int j = 0; j < 4; j++)
                bf[j] = *(const bf16x8*)(&Bs1[(wn + 16 * j + m16) * 32 + qd * 8]);
#pragma unroll
            for (int i = 0; i < 4; i++)
#pragma unroll
                for (int j = 0; j < 4; j++)
                    acc[i][j] = __builtin_amdgcn_mfma_f32_16x16x32_bf16(
                        af[i], bf[j], acc[i][j], 0, 0, 0);
        }
    }
    __syncthreads();                             // all waves done with As/Bs (CsT aliases)

    // epilogue write: +b_enc, relu -> CsT[col][row], one b64 per acc quad.
    // C/D layout: col=lane&15 (within 16j), row=qd*4+r (within 16i)
#pragma unroll
    for (int j = 0; j < 4; j++) {
        const int col = wn + 16 * j + m16;
        const float bc = benc[n0 + col];
#pragma unroll
        for (int i = 0; i < 4; i++) {
            const int rbase = wm + 16 * i + qd * 4;
            const f32x4 a = acc[i][j];
            f16x4 v;
            v[0] = (_Float16)fmaxf(a[0] + bc, 0.0f);
            v[1] = (_Float16)fmaxf(a[1] + bc, 0.0f);
            v[2] = (_Float16)fmaxf(a[2] + bc, 0.0f);
            v[3] = (_Float16)fmaxf(a[3] + bc, 0.0f);
            *(f16x4*)(&CsT[col * 136 + rbase]) = v;
        }
    }
    __syncthreads();

    const int b = m0 >> 8;                       // batch
    const int tloc = m0 & 255;                   // 0 or 128 within batch
    const int wbase = (tloc == 0) ? 0 : 64;

    // per-column window sums: thread owns col = tid&127, row-half = tid>>7.
    // half 0: rows 0..65 -> windows 0..31 (local t0=0..62)
    // half 1: rows 64..127 -> windows 32..62 (local t0=64..124)
    const int col = tid & 127, half = tid >> 7;
    const _Float16* cp = &CsT[col * 136 + half * 64];
    f16x8 r8[8];
#pragma unroll
    for (int k = 0; k < 8; k++) r8[k] = *(const f16x8*)(cp + 8 * k);
    float f[66];
#pragma unroll
    for (int k = 0; k < 8; k++)
#pragma unroll
        for (int e = 0; e < 8; e++) f[8 * k + e] = (float)r8[k][e];
    if (half == 0) {
        const f16x2 t2 = *(const f16x2*)(cp + 64);
        f[64] = (float)t2[0]; f[65] = (float)t2[1];
    } else { f[64] = 0.f; f[65] = 0.f; }

    _Float16* wrow = (_Float16*)wsum;
#pragma unroll
    for (int w2 = 0; w2 < 31; w2++) {
        const float s = (f[2 * w2] + f[2 * w2 + 1]) + (f[2 * w2 + 2] + f[2 * w2 + 3]);
        wrow[(size_t)(b * NWIN + wbase + half * 32 + w2) * DICT + n0 + col] = (_Float16)s;
    }
    if (half == 0) {
        const float s = (f[62] + f[63]) + (f[64] + f[65]);
        wrow[(size_t)(b * NWIN + wbase + 31) * DICT + n0 + col] = (_Float16)s;
    }

    // crossing-window rows: tloc==0 -> local rows 126,127 (slots 0,1);
    //                       tloc==128 -> local rows 0,1 (slots 2,3)
    {
        const int rr = half;                      // two rows via the two halves
        const int lr0 = (tloc == 0) ? 126 : 0;
        const int slot0 = (tloc == 0) ? 0 : 2;
        const _Float16 v = CsT[col * 136 + lr0 + rr];
        ((_Float16*)zedge)[(size_t)(b * 4 + slot0 + rr) * DICT + n0 + col] = v;
    }

    // z~ cols 0..127 for the zero-fill rule (n-block 0 only): rows half*64..+63
    if (n0 == 0) {
#pragma unroll
        for (int k = 0; k < 8; k++)
#pragma unroll
            for (int e = 0; e < 8; e++)
                ((_Float16*)zh128)[(size_t)(m0 + half * 64 + 8 * k + e) * 128 + col]
                    = r8[k][e];
    }
}

// ---------------------------------------------------------------------------
// K2+K3 fused: per-window screen (approx wsum, tau~ via bit search, candidate
// set in LDS) then exact fp32 recompute + exact top-64 in the same block.
// ---------------------------------------------------------------------------
__global__ __launch_bounds__(256) void win_select(
    const unsigned short* __restrict__ wsum, const unsigned short* __restrict__ zedge,
    const float* __restrict__ x, const float* __restrict__ W,
    const float* __restrict__ benc, const float* __restrict__ bdec,
    int* __restrict__ win_idx, float* __restrict__ ztab)
{
    const int wid = blockIdx.x;
    const int b = wid / NWIN, w = wid % NWIN;
    const int t0 = 2 * w;
    const int tid = threadIdx.x;
    const int lane = tid & 63, wvi = tid >> 6;

    __shared__ int cand[SCAP];
    __shared__ float swsum[SCAP];
    __shared__ float sz[SCAP][4];
    __shared__ int sd[SCAP];
    __shared__ int red[4];
    __shared__ int s_cnt, s_n1, s_eqc;
    __shared__ int eq_d[SCAP], eq_s[SCAP];
    __shared__ int out_slot[64];

    // ---- screen phase: approx wsum, 64th-largest, band ----
    float wv[64];
    if (w != 63) {
        const _Float16* row = (const _Float16*)wsum + (size_t)wid * DICT;
#pragma unroll
        for (int c = 0; c < 8; c++) {
            const f16x8 r0 = *(const f16x8*)(row + (c * 256 + tid) * 8);
#pragma unroll
            for (int e = 0; e < 8; e++) wv[c * 8 + e] = (float)r0[e];
        }
    } else {
        const _Float16* e0 = (const _Float16*)zedge + (size_t)b * 4 * DICT;
#pragma unroll
        for (int c = 0; c < 8; c++) {
            const int d8 = (c * 256 + tid) * 8;
            const f16x8 r0 = *(const f16x8*)(e0 + d8);
            const f16x8 r1 = *(const f16x8*)(e0 + DICT + d8);
            const f16x8 r2 = *(const f16x8*)(e0 + 2 * DICT + d8);
            const f16x8 r3 = *(const f16x8*)(e0 + 3 * DICT + d8);
#pragma unroll
            for (int e = 0; e < 8; e++)
                wv[c * 8 + e] = (((float)r0[e] + (float)r1[e]) + (float)r2[e]) + (float)r3[e];
        }
    }
    {
        unsigned lo = 0u, hi = 0x43000000u;        // 128.0f
        while (lo < hi) {
            const unsigned mid = (lo + hi) >> 1;
            const float fm = __uint_as_float(mid);
            int c = 0;
#pragma unroll
            for (int j = 0; j < 64; j++) c += (wv[j] > fm) ? 1 : 0;
            for (int off = 32; off > 0; off >>= 1) c += __shfl_down(c, off);
            if ((tid & 63) == 0) red[tid >> 6] = c;
            __syncthreads();
            const int tot = red[0] + red[1] + red[2] + red[3];
            __syncthreads();
            if (tot >= 64) lo = mid + 1; else hi = mid;
        }
        const float thr = __uint_as_float(lo) - BAND;
        if (tid == 0) s_cnt = 0;
        __syncthreads();
#pragma unroll
        for (int c = 0; c < 8; c++) {
#pragma unroll
            for (int e = 0; e < 8; e++) {
                if (wv[c * 8 + e] > thr) {
                    const int s = atomicAdd(&s_cnt, 1);
                    if (s < SCAP) cand[s] = (c * 256 + tid) * 8 + e;
                }
            }
        }
        __syncthreads();
    }
    const int cnt = min(s_cnt, SCAP);

    // ---- exact phase: fp32 recompute over candidates ----
    const float* xrow = x + (size_t)(b * SEQ + t0) * CDIM;
    float4 xd[4][3];
#pragma unroll
    for (int e = 0; e < 3; e++) {
        const int c = lane * 4 + e * 256;
        const float4 bd = *(const float4*)(bdec + c);
#pragma unroll
        for (int r = 0; r < 4; r++) {
            const float4 xv = *(const float4*)(xrow + r * CDIM + c);
            xd[r][e].x = xv.x - bd.x; xd[r][e].y = xv.y - bd.y;
            xd[r][e].z = xv.z - bd.z; xd[r][e].w = xv.w - bd.w;
        }
    }

    int s = wvi;
    int dcur = -1;
    float4 wv0, wv1, wv2;
    if (s < cnt) {
        dcur = cand[s];
        const float* wr = W + (size_t)dcur * CDIM + lane * 4;
        wv0 = *(const float4*)(wr);
        wv1 = *(const float4*)(wr + 256);
        wv2 = *(const float4*)(wr + 512);
    }
    while (s < cnt) {
        const int snx = s + 4;
        int dnx = -1;
        float4 wn0, wn1, wn2;
        if (snx < cnt) {
            dnx = cand[snx];
            const float* wr = W + (size_t)dnx * CDIM + lane * 4;
            wn0 = *(const float4*)(wr);
            wn1 = *(const float4*)(wr + 256);
            wn2 = *(const float4*)(wr + 512);
        }
        float a0 = 0.f, a1 = 0.f, a2 = 0.f, a3 = 0.f;
        {
            const float4 wvv[3] = {wv0, wv1, wv2};
#pragma unroll
            for (int e = 0; e < 3; e++) {
                a0 = fmaf(xd[0][e].x, wvv[e].x, a0);
                a0 = fmaf(xd[0][e].y, wvv[e].y, a0);
                a0 = fmaf(xd[0][e].z, wvv[e].z, a0);
                a0 = fmaf(xd[0][e].w, wvv[e].w, a0);
                a1 = fmaf(xd[1][e].x, wvv[e].x, a1);
                a1 = fmaf(xd[1][e].y, wvv[e].y, a1);
                a1 = fmaf(xd[1][e].z, wvv[e].z, a1);
                a1 = fmaf(xd[1][e].w, wvv[e].w, a1);
                a2 = fmaf(xd[2][e].x, wvv[e].x, a2);
                a2 = fmaf(xd[2][e].y, wvv[e].y, a2);
                a2 = fmaf(xd[2][e].z, wvv[e].z, a2);
                a2 = fmaf(xd[2][e].w, wvv[e].w, a2);
                a3 = fmaf(xd[3][e].x, wvv[e].x, a3);
                a3 = fmaf(xd[3][e].y, wvv[e].y, a3);
                a3 = fmaf(xd[3][e].z, wvv[e].z, a3);
                a3 = fmaf(xd[3][e].w, wvv[e].w, a3);
            }
        }
#pragma unroll
        for (int off = 32; off > 0; off >>= 1) {
            a0 += __shfl_xor(a0, off); a1 += __shfl_xor(a1, off);
            a2 += __shfl_xor(a2, off); a3 += __shfl_xor(a3, off);
        }
        if (lane == 0) {
            const float be = benc[dcur];
            const float z0 = fmaxf(a0 + be, 0.f), z1 = fmaxf(a1 + be, 0.f);
            const float z2 = fmaxf(a2 + be, 0.f), z3 = fmaxf(a3 + be, 0.f);
            sd[s] = dcur;
            sz[s][0] = z0; sz[s][1] = z1; sz[s][2] = z2; sz[s][3] = z3;
            swsum[s] = ((z0 + z1) + z2) + z3;
        }
        s = snx; dcur = dnx;
        wv0 = wn0; wv1 = wn1; wv2 = wn2;
    }
    __syncthreads();

    // exact top-64 (tie: lowest feature index), identical to prior rounds
    const float v = (tid < cnt) ? swsum[tid] : -1.0f;
    unsigned lo = 0u, hi = 0x43000000u;
    while (lo < hi) {
        const unsigned mid = (lo + hi) >> 1;
        const float fm = __uint_as_float(mid);
        int c = (v > fm) ? 1 : 0;
        for (int off = 32; off > 0; off >>= 1) c += __shfl_down(c, off);
        if ((tid & 63) == 0) red[tid >> 6] = c;
        __syncthreads();
        const int tot = red[0] + red[1] + red[2] + red[3];
        __syncthreads();
        if (tot >= 64) lo = mid + 1; else hi = mid;
    }
    const float tau = __uint_as_float(lo);

    if (tid == 0) { s_n1 = 0; s_eqc = 0; }
    __syncthreads();
    if (tid < cnt) {
        if (v > tau) { const int sl = atomicAdd(&s_n1, 1); out_slot[sl] = tid; }
        else if (v == tau) {
            const int sl = atomicAdd(&s_eqc, 1);
            if (sl < SCAP) { eq_d[sl] = sd[tid]; eq_s[sl] = tid; }
        }
    }
    __syncthreads();
    if (tid == 0) {
        const int n1 = s_n1, need = 64 - n1;
        int ec = min(s_eqc, SCAP);
        for (int a = 0; a < need; a++) {          // lowest-index-first fill
            int best = a;
            for (int q = a + 1; q < ec; q++)
                if (eq_d[q] < eq_d[best]) best = q;
            int td = eq_d[a]; eq_d[a] = eq_d[best]; eq_d[best] = td;
            int ts = eq_s[a]; eq_s[a] = eq_s[best]; eq_s[best] = ts;
            out_slot[n1 + a] = eq_s[a];
        }
    }
    __syncthreads();
    if (tid < 64) {
        const int sl = out_slot[tid];
        win_idx[wid * 64 + tid] = sd[sl];
        float* zt = ztab + (size_t)(wid * 64 + tid) * 4;
        zt[0] = sz[sl][0]; zt[1] = sz[sl][1]; zt[2] = sz[sl][2]; zt[3] = sz[sl][3];
    }
}

// ---------------------------------------------------------------------------
// K5: per-token final top-64 of fv. Selected values exact (ztab); zero-fill
// values approx from fp16 zh128 (fill indices provably < 128; tol 0.109).
// ---------------------------------------------------------------------------
__global__ __launch_bounds__(64) void tok_topk(
    const int* __restrict__ win_idx, const float* __restrict__ ztab,
    const unsigned short* __restrict__ zh128,
    int* __restrict__ tok_idx, float* __restrict__ tok_val)
{
    const int bid = blockIdx.x;            // token = b*256 + t
    const int t = bid & 255, b = bid >> 8;
    const int lane = threadIdx.x;
    const int wlo = (t >= 2) ? ((t - 2) >> 1) : 0;
    int whi = t >> 1; if (whi > NWIN - 1) whi = NWIN - 1;

    __shared__ int l1[64], l2[64];
    __shared__ int out_i[64];
    __shared__ float out_v[64];
    __shared__ int eq_i[130];
    __shared__ float eq_v[130];
    __shared__ int cnt, eqc;

    const int g1 = (b * NWIN + wlo) * 64 + lane;
    const int idx1 = win_idx[g1];
    const float z1 = ztab[(size_t)g1 * 4 + (t - 2 * wlo)];
    const bool valid2 = (whi != wlo);
    int idx2 = -1; float z2 = 0.f;
    if (valid2) {
        const int g2 = (b * NWIN + whi) * 64 + lane;
        idx2 = win_idx[g2];
        z2 = ztab[(size_t)g2 * 4 + (t - 2 * whi)];
    }
    l1[lane] = idx1; l2[lane] = idx2;
    if (lane == 0) { cnt = 0; eqc = 0; }
    __syncthreads();

    bool in2 = false, dup2 = false;
    for (int j = 0; j < 64; j++) {
        in2  |= (idx1 == l2[j]);
        dup2 |= (idx2 == l1[j]);
    }
    const float fv1 = in2 ? 2.0f * z1 : z1;
    const bool c2 = valid2 && !dup2;
    const float fv2 = c2 ? z2 : 0.0f;
    const bool pos1 = (fv1 > 0.0f);
    const bool pos2 = c2 && (fv2 > 0.0f);
    const unsigned long long m1 = __ballot(pos1);
    const unsigned long long m2 = __ballot(pos2);
    const int npos = __popcll(m1) + __popcll(m2);

    if (npos > 64) {
        unsigned lo = 0u, hi = 0x43000000u;
        while (lo < hi) {
            const unsigned mid = (lo + hi) >> 1;
            const float fm = __uint_as_float(mid);
            const int c = __popcll(__ballot(pos1 && fv1 > fm)) +
                          __popcll(__ballot(pos2 && fv2 > fm));
            if (c >= 64) lo = mid + 1; else hi = mid;
        }
        const float tau = __uint_as_float(lo);
        const int n1 = __popcll(__ballot(pos1 && fv1 > tau)) +
                       __popcll(__ballot(pos2 && fv2 > tau));
        if (pos1 && fv1 > tau) { const int s = atomicAdd(&cnt, 1); out_i[s] = idx1; out_v[s] = z1; }
        if (pos2 && fv2 > tau) { const int s = atomicAdd(&cnt, 1); out_i[s] = idx2; out_v[s] = z2; }
        if (pos1 && fv1 == tau) { const int s = atomicAdd(&eqc, 1); if (s < 130) { eq_i[s] = idx1; eq_v[s] = z1; } }
        if (pos2 && fv2 == tau) { const int s = atomicAdd(&eqc, 1); if (s < 130) { eq_i[s] = idx2; eq_v[s] = z2; } }
        __syncthreads();
        if (lane == 0) {
            const int need = 64 - n1;
            int ec = (eqc < 130) ? eqc : 130;
            for (int a = 0; a < need; a++) {
                int best = a;
                for (int q = a + 1; q < ec; q++)
                    if (eq_i[q] < eq_i[best]) best = q;
                const int ti = eq_i[a]; eq_i[a] = eq_i[best]; eq_i[best] = ti;
                const float tv = eq_v[a]; eq_v[a] = eq_v[best]; eq_v[best] = tv;
                out_i[n1 + a] = eq_i[a]; out_v[n1 + a] = eq_v[a];
            }
        }
    } else {
        if (pos1) { const int s = atomicAdd(&cnt, 1); out_i[s] = idx1; out_v[s] = z1; }
        if (pos2) { const int s = atomicAdd(&cnt, 1); out_i[s] = idx2; out_v[s] = z2; }
        const int need = 64 - npos;
        const int d1 = lane, d2 = lane + 64;
        bool ip1 = false, ip2 = false;
        for (int j = 0; j < 64; j++) {
            const int o1 = l1[j]; const bool p1 = (m1 >> j) & 1ull;
            const int o2 = l2[j]; const bool p2 = (m2 >> j) & 1ull;
            ip1 |= (p1 && o1 == d1) || (p2 && o2 == d1);
            ip2 |= (p1 && o1 == d2) || (p2 && o2 == d2);
        }
        const unsigned long long av1 = __ballot(!ip1);
        const unsigned long long av2 = __ballot(!ip2);
        const unsigned long long below = (1ull << lane) - 1ull;
        const int r1 = __popcll(av1 & below);
        const int na1 = __popcll(av1);
        const int r2 = na1 + __popcll(av2 & below);
        if (!ip1 && r1 < need) {
            bool incand = false;
            for (int j = 0; j < 64; j++) incand |= (l1[j] == d1) || (l2[j] == d1);
            // in-candidate fv==0 implies exact z==0; else use fp16 approx value
            const float zv = incand ? 0.0f
                : (float)((const _Float16*)zh128)[(size_t)bid * 128 + d1];
            const int s = atomicAdd(&cnt, 1); out_i[s] = d1; out_v[s] = zv;
        }
        if (!ip2 && r2 < need) {
            bool incand = false;
            for (int j = 0; j < 64; j++) incand |= (l1[j] == d2) || (l2[j] == d2);
            const float zv = incand ? 0.0f
                : (float)((const _Float16*)zh128)[(size_t)bid * 128 + d2];
            const int s = atomicAdd(&cnt, 1); out_i[s] = d2; out_v[s] = zv;
        }
    }
    __syncthreads();
    tok_idx[bid * 64 + lane] = out_i[lane];
    tok_val[bid * 64 + lane] = out_v[lane];
}

// ---------------------------------------------------------------------------
// K6: recon from bf16 W rows (coalesced uint2 per row, 192 thr/block)
// ---------------------------------------------------------------------------
__global__ __launch_bounds__(192) void recon_k(
    const int* __restrict__ tok_idx, const float* __restrict__ tok_val,
    const unsigned short* __restrict__ Wb, const float* __restrict__ bdec,
    float* __restrict__ recon)
{
    const int bid = blockIdx.x;
    const int tid = threadIdx.x;          // 0..191
    __shared__ int si[64];
    __shared__ float sv[64];
    if (tid < 64) { si[tid] = tok_idx[bid * 64 + tid]; sv[tid] = tok_val[bid * 64 + tid]; }
    __syncthreads();

    const int c = tid * 4;                // 4 consecutive cols, 8B aligned in Wb
    const float4 bd = *(const float4*)(bdec + c);
    float a0 = bd.x, a1 = bd.y, a2 = bd.z, a3 = bd.w;
#pragma unroll 8
    for (int j = 0; j < 64; j++) {
        const uint2 pv = *(const uint2*)(Wb + (size_t)si[j] * CDIM + c);
        const float vj = sv[j];
        a0 = fmaf(vj, bf2f((unsigned short)(pv.x & 0xffffu)), a0);
        a1 = fmaf(vj, bf2f((unsigned short)(pv.x >> 16)), a1);
        a2 = fmaf(vj, bf2f((unsigned short)(pv.y & 0xffffu)), a2);
        a3 = fmaf(vj, bf2f((unsigned short)(pv.y >> 16)), a3);
    }
    float4 o; o.x = a0; o.y = a1; o.z = a2; o.w = a3;
    *(float4*)(recon + (size_t)bid * CDIM + c) = o;
}

// ---------------------------------------------------------------------------
// K7: fused zero + scatter (replaces memset + scatter; no write amplification)
// ---------------------------------------------------------------------------
__global__ __launch_bounds__(256) void zero_scatter(
    const int* __restrict__ tok_idx, const float* __restrict__ tok_val,
    float* __restrict__ enc)
{
    const int bid = blockIdx.x;
    const int tid = threadIdx.x;
    float* row = enc + (size_t)bid * DICT;
    const float4 z4 = {0.f, 0.f, 0.f, 0.f};
#pragma unroll
    for (int k = 0; k < 16; k++)                 // 256 thr * 16 * 4 = 16384
        *(float4*)(row + (k * 256 + tid) * 4) = z4;
    __syncthreads();
    if (tid < 64)
        row[tok_idx[bid * 64 + tid]] = tok_val[bid * 64 + tid];
}

// ---------------------------------------------------------------------------
extern "C" void kernel_launch(void* const* d_in, const int* in_sizes, int n_in,
                              void* d_out, int out_size, void* d_ws, size_t ws_size,
                              hipStream_t stream)
{
    const float* x    = (const float*)d_in[0];
    const float* Wenc = (const float*)d_in[1];
    const float* benc = (const float*)d_in[2];
    const float* bdec = (const float*)d_in[4];
    (void)in_sizes; (void)n_in; (void)out_size; (void)ws_size;

    float* recon = (float*)d_out;
    float* enc   = recon + (size_t)NTOK * CDIM;          // 134,217,728 bytes

    // scratch layout inside the enc output region (all consumed pre-zero)
    char* base = (char*)enc;
    unsigned short* wsum  = (unsigned short*)(base);                 // 33,292,288
    unsigned short* Wb    = (unsigned short*)(base + 33292288);      // 25,165,824
    unsigned short* xb    = (unsigned short*)(base + 58458112);      //  3,145,728
    unsigned short* zedge = (unsigned short*)(base + 61603840);      //  1,048,576
    unsigned short* zh128 = (unsigned short*)(base + 62652416);      //    524,288
    int*   wini           = (int*)(base + 63176704);                 //    260,096
    float* ztab           = (float*)(base + 63436800);               //  1,040,384

    // tok lists must survive the zeroing -> d_ws (1.0 MB)
    int*   tok_i = (int*)d_ws;
    float* tok_v = (float*)((char*)d_ws + (size_t)NTOK * 64 * 4);

    prep<<<dim3(6912), 256, 0, stream>>>(Wenc, x, bdec, Wb, xb);
    gemm_bf16<<<dim3(NTOK / 128, DICT / 128), 256, 0, stream>>>(xb, Wb, benc,
                                                                wsum, zedge, zh128);
    win_select<<<dim3(BATCH * NWIN), 256, 0, stream>>>(wsum, zedge, x, Wenc,
                                                       benc, bdec, wini, ztab);
    tok_topk<<<dim3(NTOK), 64, 0, stream>>>(wini, ztab, zh128, tok_i, tok_v);
    recon_k<<<dim3(NTOK), 192, 0, stream>>>(tok_i, tok_v, Wb, bdec, recon);
    zero_scatter<<<dim3(NTOK), 256, 0, stream>>>(tok_i, tok_v, enc);
}